// Round 8
// baseline (411.817 us; speedup 1.0000x reference)
//
#include <hip/hip_runtime.h>

#define NN 1024
#define FF 64
#define NBT 64
#define INV_LN2 1.44269504088896f

typedef float f32x4 __attribute__((ext_vector_type(4)));
typedef short s16x8 __attribute__((ext_vector_type(8)));

__device__ __forceinline__ short f2bf(float f) {
    unsigned u = __builtin_bit_cast(unsigned, f);
    u = (u + 0x7FFFu + ((u >> 16) & 1u)) >> 16;
    return (short)u;
}

// Kernel 1: Wh = h @ W (fp32 compute). Outputs:
//   WhT  bf16  [bt][c][j]   (transposed so k2 B-fragments are contiguous in j)
//   s1,s2 fp32 [bt][j]      (Wh.a1, Wh.a2) PRE-SCALED by 1/ln2 (log2 domain:
//   leaky_relu commutes with positive scaling, so k2 uses raw v_exp_f32).
__global__ __launch_bounds__(256) void k1(const float* __restrict__ h,
                                          const float* __restrict__ W,
                                          const float* __restrict__ a,
                                          short* __restrict__ WhT,
                                          float* __restrict__ s1g,
                                          float* __restrict__ s2g) {
    __shared__ float Wl[64 * 64];   // [k][c]
    __shared__ float al[128];
    __shared__ float s1sh[128], s2sh[128];
    const int blk = blockIdx.x;
    const int bt = blk >> 3;
    const int rbase = (blk & 7) * 128;
    const int t = threadIdx.x;

    for (int i = t; i < 1024; i += 256)
        ((f32x4*)Wl)[i] = ((const f32x4*)W)[i];
    if (t < 32) ((f32x4*)al)[t] = ((const f32x4*)a)[t];
    __syncthreads();

    const int row = rbase + (t & 127);
    const int half = t >> 7;           // 0: c 0..31, 1: c 32..63
    const float* hrow = h + ((size_t)bt * NN + row) * FF;
    float hv[64];
#pragma unroll
    for (int i = 0; i < 16; i++)
        ((f32x4*)hv)[i] = ((const f32x4*)hrow)[i];

    float s1 = 0.f, s2 = 0.f;
    short* wt = WhT + (size_t)bt * FF * NN + row;
#pragma unroll
    for (int cgi = 0; cgi < 8; cgi++) {
        const int cg = half * 8 + cgi;       // float4 group of columns
        f32x4 acc = {0.f, 0.f, 0.f, 0.f};
#pragma unroll
        for (int k = 0; k < 64; k++) {
            f32x4 w4 = ((const f32x4*)Wl)[k * 16 + cg];  // broadcast read
            acc += hv[k] * w4;
        }
        const int c0 = cg * 4;
        s1 += acc.x * al[c0] + acc.y * al[c0 + 1] + acc.z * al[c0 + 2] + acc.w * al[c0 + 3];
        s2 += acc.x * al[64 + c0] + acc.y * al[64 + c0 + 1] + acc.z * al[64 + c0 + 2] + acc.w * al[64 + c0 + 3];
        wt[(size_t)(c0 + 0) * NN] = f2bf(acc.x);
        wt[(size_t)(c0 + 1) * NN] = f2bf(acc.y);
        wt[(size_t)(c0 + 2) * NN] = f2bf(acc.z);
        wt[(size_t)(c0 + 3) * NN] = f2bf(acc.w);
    }
    if (half == 1) { s1sh[t & 127] = s1; s2sh[t & 127] = s2; }
    __syncthreads();
    if (half == 0) {
        s1g[bt * NN + row] = (s1 + s1sh[t]) * INV_LN2;
        s2g[bt * NN + row] = (s2 + s2sh[t]) * INV_LN2;
    }
}

// Kernel 2: masked-softmax attention + P @ Wh via bf16 MFMA, + elu.
// == BARRIER-FREE main loop via intra-wave P shuffle ==
// Key observation: wave wv's staging threads (row = wv*16+(l>>2), chunk
// (l&3)*8) compute EXACTLY the rows wave wv's A-fragment needs
// (row = wv*16+(l&15), chunk (l>>4)*8). The staging->fragment exchange is
// the fixed lane permutation srcLane = ((l&15)<<2)|(l>>4) -- 4 ds_bpermute
// ops replace the Pa LDS write + barrier + read. B-fragments load straight
// from global (WhT panel L2-resident; 4 q-lanes per row hit one 64B line).
// => ZERO barriers per tile (r5-r7 paid 32; r6 showed the loop floor ~57us
// was barrier/LDS-structure, not arithmetic). adj keeps r7's proven paired
// depth-2 prefetch in explicit named registers (r1/r2's collapse was the
// compiler dropping in-flight loads at VGPR=44).
// grid 1024 = 64 bt x 16 row-tiles; 256 thr = 4 independent waves.
// Rowsum via 5th MFMA (B=ones). XCD swizzle for WhT L2 locality.
__global__ __launch_bounds__(256, 4) void k2(const int* __restrict__ adj,
                                             const short* __restrict__ WhT,
                                             const float* __restrict__ s1g,
                                             const float* __restrict__ s2g,
                                             float* __restrict__ out) {
    __shared__ float s2l[NN];

    const int bxl = blockIdx.x;
    const int bx = (bxl & 7) * 128 + (bxl >> 3);   // bijective XCD swizzle (1024 = 8*128)
    const int bt = bx >> 4;
    const int ibase = (bx & 15) * 64;
    const int t = threadIdx.x;
    const int wv = t >> 6;
    const int l = t & 63;

    // stage the full s2 row for this batch (shared by all 4 waves)
    ((f32x4*)s2l)[t] = ((const f32x4*)(s2g + (size_t)bt * NN))[t];

    // staging identity: this lane COMPUTES P row sr, j-chunk jc
    const int sr = wv * 16 + (l >> 2);
    const int jc = (l & 3) * 8;
    const float s1v = s1g[bt * NN + ibase + sr];   // log2-domain
    const int* adjp = adj + ((size_t)bt * NN + ibase + sr) * NN + jc;

    // MFMA identity: this lane CONSUMES row wv*16+m, k-octet q
    const int m = l & 15;
    const int q = l >> 4;
    const int srcLane = ((l & 15) << 2) | (l >> 4);   // staging lane holding my octet

    // B-fragment base: rows g*16+m, cols q*8 (+ jt*32 per tile)
    const short* whp = WhT + (size_t)bt * FF * NN + (size_t)m * NN + q * 8;

    f32x4 acc0 = {0.f, 0.f, 0.f, 0.f};
    f32x4 acc1 = {0.f, 0.f, 0.f, 0.f};
    f32x4 acc2 = {0.f, 0.f, 0.f, 0.f};
    f32x4 acc3 = {0.f, 0.f, 0.f, 0.f};
    f32x4 accR = {0.f, 0.f, 0.f, 0.f};
    const s16x8 ones = {0x3F80, 0x3F80, 0x3F80, 0x3F80, 0x3F80, 0x3F80, 0x3F80, 0x3F80};

    // adj prefetch for PAIR 0 (tiles 0,1) -- explicit named regs, depth 2 tiles
    int4 ca0 = *(const int4*)(adjp);
    int4 ca1 = *(const int4*)(adjp + 4);
    int4 ca2 = *(const int4*)(adjp + 32);
    int4 ca3 = *(const int4*)(adjp + 36);
    // B-fragment prefetch for tile 0
    s16x8 cb0 = *(const s16x8*)(whp);
    s16x8 cb1 = *(const s16x8*)(whp + 16 * NN);
    s16x8 cb2 = *(const s16x8*)(whp + 32 * NN);
    s16x8 cb3 = *(const s16x8*)(whp + 48 * NN);

    __syncthreads();   // s2l ready (the ONLY barrier in this kernel)

    for (int pp = 0; pp < 16; pp++) {
        // issue next pair's adj loads: ~2 tiles of slack to cover HBM miss
        const int nb = (pp < 15 ? pp + 1 : 15) * 64;   // dup last pair: harmless
        int4 na0 = *(const int4*)(adjp + nb);
        int4 na1 = *(const int4*)(adjp + nb + 4);
        int4 na2 = *(const int4*)(adjp + nb + 32);
        int4 na3 = *(const int4*)(adjp + nb + 36);

#pragma unroll
        for (int u = 0; u < 2; u++) {
            const int jt = pp * 2 + u;
            const int4 xa0 = (u == 0) ? ca0 : ca2;
            const int4 xa1 = (u == 0) ? ca1 : ca3;

            // B prefetch for tile jt+1 (L2-hit ~200cyc, consumed next tile)
            const int jn = (jt < 31 ? jt + 1 : 31) * 32;
            s16x8 nb0 = *(const s16x8*)(whp + jn);
            s16x8 nb1 = *(const s16x8*)(whp + 16 * NN + jn);
            s16x8 nb2 = *(const s16x8*)(whp + 32 * NN + jn);
            s16x8 nb3 = *(const s16x8*)(whp + 48 * NN + jn);

            // P = adj ? exp2(leaky(s1+s2)) : 0  (log2 domain, no max-sub)
            int aj[8] = {xa0.x, xa0.y, xa0.z, xa0.w, xa1.x, xa1.y, xa1.z, xa1.w};
            f32x4 s2a = *(const f32x4*)&s2l[jt * 32 + jc];
            f32x4 s2b = *(const f32x4*)&s2l[jt * 32 + jc + 4];
            float sv[8] = {s2a.x, s2a.y, s2a.z, s2a.w, s2b.x, s2b.y, s2b.z, s2b.w};
            s16x8 pbv;
#pragma unroll
            for (int k = 0; k < 8; k++) {
                float e = s1v + sv[k];
                e = fmaxf(e, 0.2f * e);            // leaky_relu (scale-commutes)
                e = fminf(e, 86.f);                // paranoia clamp, never active
                float p = (aj[k] > 0) ? exp2f(e) : 0.f;
                pbv[k] = f2bf(p);
            }

            // staging layout -> A-fragment layout: one fixed lane permutation
            // (intra-wave: wave's 64 lanes hold exactly its 16 rows x 4 octets)
            union { s16x8 v; int d[4]; } pu, au;
            pu.v = pbv;
#pragma unroll
            for (int w = 0; w < 4; w++)
                au.d[w] = __shfl(pu.d[w], srcLane);
            const s16x8 af = au.v;

            acc0 = __builtin_amdgcn_mfma_f32_16x16x32_bf16(af, cb0, acc0, 0, 0, 0);
            acc1 = __builtin_amdgcn_mfma_f32_16x16x32_bf16(af, cb1, acc1, 0, 0, 0);
            acc2 = __builtin_amdgcn_mfma_f32_16x16x32_bf16(af, cb2, acc2, 0, 0, 0);
            acc3 = __builtin_amdgcn_mfma_f32_16x16x32_bf16(af, cb3, acc3, 0, 0, 0);
            accR = __builtin_amdgcn_mfma_f32_16x16x32_bf16(af, ones, accR, 0, 0, 0);

            cb0 = nb0; cb1 = nb1; cb2 = nb2; cb3 = nb3;
        }
        ca0 = na0; ca1 = na1; ca2 = na2; ca3 = na3;
    }

    // accR[e] = rowsum(wv*16 + q*4 + e) -- exactly this lane's C rows
    float rinv[4];
#pragma unroll
    for (int e = 0; e < 4; e++)
        rinv[e] = accR[e] > 0.f ? 1.f / accR[e] : 0.f;

    float* outp = out + ((size_t)bt * NN + ibase + wv * 16 + q * 4) * FF + m;
#pragma unroll
    for (int e = 0; e < 4; e++) {
        float v0 = acc0[e] * rinv[e];
        float v1 = acc1[e] * rinv[e];
        float v2 = acc2[e] * rinv[e];
        float v3 = acc3[e] * rinv[e];
        v0 = v0 > 0.f ? v0 : expm1f(v0);
        v1 = v1 > 0.f ? v1 : expm1f(v1);
        v2 = v2 > 0.f ? v2 : expm1f(v2);
        v3 = v3 > 0.f ? v3 : expm1f(v3);
        float* o = outp + (size_t)e * FF;
        o[0]  = v0;
        o[16] = v1;
        o[32] = v2;
        o[48] = v3;
    }
}

extern "C" void kernel_launch(void* const* d_in, const int* in_sizes, int n_in,
                              void* d_out, int out_size, void* d_ws, size_t ws_size,
                              hipStream_t stream) {
    const float* h  = (const float*)d_in[0];
    const int*  adj = (const int*)d_in[1];
    const float* W  = (const float*)d_in[2];
    const float* a  = (const float*)d_in[3];
    float* out = (float*)d_out;

    short* WhT = (short*)d_ws;                                      // 8 MB
    float* s1  = (float*)((char*)d_ws + (size_t)NBT * FF * NN * 2); // 256 KB
    float* s2  = s1 + NBT * NN;                                     // 256 KB

    k1<<<512, 256, 0, stream>>>(h, W, a, WhT, s1, s2);
    k2<<<1024, 256, 0, stream>>>(adj, WhT, s1, s2, out);
}

// Round 10
// 395.037 us; speedup vs baseline: 1.0425x; 1.0425x over previous
//
#include <hip/hip_runtime.h>

#define NN 1024
#define FF 64
#define NBT 64
#define INV_LN2 1.44269504088896f

typedef float f32x4 __attribute__((ext_vector_type(4)));
typedef short s16x8 __attribute__((ext_vector_type(8)));
typedef int i32x4 __attribute__((ext_vector_type(4)));

__device__ __forceinline__ short f2bf(float f) {
    unsigned u = __builtin_bit_cast(unsigned, f);
    u = (u + 0x7FFFu + ((u >> 16) & 1u)) >> 16;
    return (short)u;
}

// non-temporal 16B load: must use a clang ext_vector_type (HIP's int4 is a
// class and __builtin_nontemporal_load rejects it -- r9 compile fail).
__device__ __forceinline__ i32x4 ntload(const int* p) {
    return __builtin_nontemporal_load((const i32x4*)p);
}

// Kernel 1: Wh = h @ W (fp32 compute). Outputs:
//   WhT  bf16  [bt][c][j]   (transposed so k2 B-fragments are contiguous in j)
//   s1,s2 fp32 [bt][j]      (Wh.a1, Wh.a2) PRE-SCALED by 1/ln2 (log2 domain:
//   leaky_relu commutes with positive scaling, so k2 uses raw v_exp_f32).
__global__ __launch_bounds__(256) void k1(const float* __restrict__ h,
                                          const float* __restrict__ W,
                                          const float* __restrict__ a,
                                          short* __restrict__ WhT,
                                          float* __restrict__ s1g,
                                          float* __restrict__ s2g) {
    __shared__ float Wl[64 * 64];   // [k][c]
    __shared__ float al[128];
    __shared__ float s1sh[128], s2sh[128];
    const int blk = blockIdx.x;
    const int bt = blk >> 3;
    const int rbase = (blk & 7) * 128;
    const int t = threadIdx.x;

    for (int i = t; i < 1024; i += 256)
        ((f32x4*)Wl)[i] = ((const f32x4*)W)[i];
    if (t < 32) ((f32x4*)al)[t] = ((const f32x4*)a)[t];
    __syncthreads();

    const int row = rbase + (t & 127);
    const int half = t >> 7;           // 0: c 0..31, 1: c 32..63
    const float* hrow = h + ((size_t)bt * NN + row) * FF;
    float hv[64];
#pragma unroll
    for (int i = 0; i < 16; i++)
        ((f32x4*)hv)[i] = ((const f32x4*)hrow)[i];

    float s1 = 0.f, s2 = 0.f;
    short* wt = WhT + (size_t)bt * FF * NN + row;
#pragma unroll
    for (int cgi = 0; cgi < 8; cgi++) {
        const int cg = half * 8 + cgi;       // float4 group of columns
        f32x4 acc = {0.f, 0.f, 0.f, 0.f};
#pragma unroll
        for (int k = 0; k < 64; k++) {
            f32x4 w4 = ((const f32x4*)Wl)[k * 16 + cg];  // broadcast read
            acc += hv[k] * w4;
        }
        const int c0 = cg * 4;
        s1 += acc.x * al[c0] + acc.y * al[c0 + 1] + acc.z * al[c0 + 2] + acc.w * al[c0 + 3];
        s2 += acc.x * al[64 + c0] + acc.y * al[64 + c0 + 1] + acc.z * al[64 + c0 + 2] + acc.w * al[64 + c0 + 3];
        wt[(size_t)(c0 + 0) * NN] = f2bf(acc.x);
        wt[(size_t)(c0 + 1) * NN] = f2bf(acc.y);
        wt[(size_t)(c0 + 2) * NN] = f2bf(acc.z);
        wt[(size_t)(c0 + 3) * NN] = f2bf(acc.w);
    }
    if (half == 1) { s1sh[t & 127] = s1; s2sh[t & 127] = s2; }
    __syncthreads();
    if (half == 0) {
        s1g[bt * NN + row] = (s1 + s1sh[t]) * INV_LN2;
        s2g[bt * NN + row] = (s2 + s2sh[t]) * INV_LN2;
    }
}

// Kernel 2: masked-softmax attention + P @ Wh via bf16 MFMA, + elu.
// == r7 structure VERBATIM (best: 409.5) + NON-TEMPORAL adj loads ==
// Theory: adj's 268MB stream evicts the WhT panels from the 4MiB XCD L2
// (1MB of panels vs ~33MB of streamed adj per XCD), so B-fragments re-fetch
// from L3/HBM at ~500+cyc against a 1-tile prefetch -> the structure-
// invariant ~1500cyc/tile stall seen in r5-r8. Evidence: r3 k2 FETCH=196MB
// vs adj's ~165MB L3-resident share -> ~30MB of WhT HBM refetch; r6 (no adj
// stream in k2) dropped to 57us. nt loads keep the stream out of L2; out
// stores are nt too (write-once). Everything else byte-identical to r7.
__global__ __launch_bounds__(256, 4) void k2(const int* __restrict__ adj,
                                             const short* __restrict__ WhT,
                                             const float* __restrict__ s1g,
                                             const float* __restrict__ s2g,
                                             float* __restrict__ out) {
    __shared__ __align__(16) short Pa[2][64 * 40];   // P tile  [i][j], pad 32->40
    __shared__ __align__(16) short Pw[2][64 * 40];   // Wh tile [c][j], pad 32->40
    __shared__ float s2l[NN];

    const int bxl = blockIdx.x;
    const int bx = (bxl & 7) * 128 + (bxl >> 3);   // bijective XCD swizzle (1024 = 8*128)
    const int bt = bx >> 4;
    const int ibase = (bx & 15) * 64;
    const int t = threadIdx.x;

    // stage the full s2 row for this batch (reused by all 32 j-tiles)
    ((f32x4*)s2l)[t] = ((const f32x4*)(s2g + (size_t)bt * NN))[t];

    const int r = t >> 2;
    const int jc = (t & 3) * 8;
    const float s1v = s1g[bt * NN + ibase + r];    // log2-domain

    const int* adjp = adj + ((size_t)bt * NN + ibase + r) * NN + jc;
    const short* whp = WhT + (size_t)bt * FF * NN + (size_t)r * NN + jc;

    const int wv = t >> 6;
    const int l = t & 63;
    const int m = l & 15;
    const int q = l >> 4;
    const int foff = (wv * 16 + m) * 40 + q * 8;   // A-frag offset within Pa[b]
    const int boff0 = (0 * 16 + m) * 40 + q * 8;   // B-frag offsets within Pw[b]
    const int boff1 = (1 * 16 + m) * 40 + q * 8;
    const int boff2 = (2 * 16 + m) * 40 + q * 8;
    const int boff3 = (3 * 16 + m) * 40 + q * 8;

    f32x4 acc0 = {0.f, 0.f, 0.f, 0.f};
    f32x4 acc1 = {0.f, 0.f, 0.f, 0.f};
    f32x4 acc2 = {0.f, 0.f, 0.f, 0.f};
    f32x4 acc3 = {0.f, 0.f, 0.f, 0.f};
    f32x4 accR = {0.f, 0.f, 0.f, 0.f};
    const s16x8 ones = {0x3F80, 0x3F80, 0x3F80, 0x3F80, 0x3F80, 0x3F80, 0x3F80, 0x3F80};

    // prefetch adj for PAIR 0 (tiles 0,1) + Wh tile 0  (adj: non-temporal)
    i32x4 ca0 = ntload(adjp);
    i32x4 ca1 = ntload(adjp + 4);
    i32x4 ca2 = ntload(adjp + 32);
    i32x4 ca3 = ntload(adjp + 36);
    int4 cw  = *(const int4*)(whp);

    __syncthreads();   // s2l ready

    for (int pp = 0; pp < 16; pp++) {
        // issue next pair's adj loads NOW: ~2 iterations to land (covers HBM)
        const int nb = (pp < 15 ? pp + 1 : 15) * 64;   // dup last pair: harmless
        i32x4 na0 = ntload(adjp + nb);
        i32x4 na1 = ntload(adjp + nb + 4);
        i32x4 na2 = ntload(adjp + nb + 32);
        i32x4 na3 = ntload(adjp + nb + 36);

        int4 nw;
#pragma unroll
        for (int u = 0; u < 2; u++) {
            const int jt = pp * 2 + u;
            const int b = jt & 1;
            const i32x4 xa0 = (u == 0) ? ca0 : ca2;
            const i32x4 xa1 = (u == 0) ? ca1 : ca3;

            // P = adj ? exp2(leaky(s1+s2)) : 0  (log2 domain, no max-sub)
            int aj[8] = {xa0.x, xa0.y, xa0.z, xa0.w, xa1.x, xa1.y, xa1.z, xa1.w};
            f32x4 s2a = *(const f32x4*)&s2l[jt * 32 + jc];
            f32x4 s2b = *(const f32x4*)&s2l[jt * 32 + jc + 4];
            float sv[8] = {s2a.x, s2a.y, s2a.z, s2a.w, s2b.x, s2b.y, s2b.z, s2b.w};
            s16x8 pbv;
#pragma unroll
            for (int k = 0; k < 8; k++) {
                float e = s1v + sv[k];
                e = fmaxf(e, 0.2f * e);            // leaky_relu (scale-commutes)
                e = fminf(e, 86.f);                // paranoia clamp, never active
                float p = (aj[k] > 0) ? exp2f(e) : 0.f;
                pbv[k] = f2bf(p);
            }
            *(s16x8*)&Pa[b][r * 40 + jc] = pbv;
            *(int4*)&Pw[b][r * 40 + jc] = cw;
            __syncthreads();                       // buf b staged (single drain point)

            // Wh prefetch for tile jt+1 (should be L2-hit once adj stops evicting)
            const int jn = (jt < 31 ? jt + 1 : 31) * 32;
            nw = *(const int4*)(whp + jn);

            s16x8 af = *(const s16x8*)&Pa[b][foff];
            acc0 = __builtin_amdgcn_mfma_f32_16x16x32_bf16(af, *(const s16x8*)&Pw[b][boff0], acc0, 0, 0, 0);
            acc1 = __builtin_amdgcn_mfma_f32_16x16x32_bf16(af, *(const s16x8*)&Pw[b][boff1], acc1, 0, 0, 0);
            acc2 = __builtin_amdgcn_mfma_f32_16x16x32_bf16(af, *(const s16x8*)&Pw[b][boff2], acc2, 0, 0, 0);
            acc3 = __builtin_amdgcn_mfma_f32_16x16x32_bf16(af, *(const s16x8*)&Pw[b][boff3], acc3, 0, 0, 0);
            accR = __builtin_amdgcn_mfma_f32_16x16x32_bf16(af, ones, accR, 0, 0, 0);
            // no second barrier: buf b is rewritten only at jt+2, after every
            // thread passed barrier jt+1; reads of buf b complete before each
            // thread's own MFMAs, which precede that barrier in program order.

            cw = nw;
        }
        ca0 = na0; ca1 = na1; ca2 = na2; ca3 = na3;
    }

    // accR[e] = rowsum(wv*16 + q*4 + e) -- exactly this lane's C rows
    float rinv[4];
#pragma unroll
    for (int e = 0; e < 4; e++)
        rinv[e] = accR[e] > 0.f ? 1.f / accR[e] : 0.f;

    float* outp = out + ((size_t)bt * NN + ibase + wv * 16 + q * 4) * FF + m;
#pragma unroll
    for (int e = 0; e < 4; e++) {
        float v0 = acc0[e] * rinv[e];
        float v1 = acc1[e] * rinv[e];
        float v2 = acc2[e] * rinv[e];
        float v3 = acc3[e] * rinv[e];
        v0 = v0 > 0.f ? v0 : expm1f(v0);
        v1 = v1 > 0.f ? v1 : expm1f(v1);
        v2 = v2 > 0.f ? v2 : expm1f(v2);
        v3 = v3 > 0.f ? v3 : expm1f(v3);
        float* o = outp + (size_t)e * FF;
        __builtin_nontemporal_store(v0, &o[0]);    // write-once: keep out of L2
        __builtin_nontemporal_store(v1, &o[16]);
        __builtin_nontemporal_store(v2, &o[32]);
        __builtin_nontemporal_store(v3, &o[48]);
    }
}

extern "C" void kernel_launch(void* const* d_in, const int* in_sizes, int n_in,
                              void* d_out, int out_size, void* d_ws, size_t ws_size,
                              hipStream_t stream) {
    const float* h  = (const float*)d_in[0];
    const int*  adj = (const int*)d_in[1];
    const float* W  = (const float*)d_in[2];
    const float* a  = (const float*)d_in[3];
    float* out = (float*)d_out;

    short* WhT = (short*)d_ws;                                      // 8 MB
    float* s1  = (float*)((char*)d_ws + (size_t)NBT * FF * NN * 2); // 256 KB
    float* s2  = s1 + NBT * NN;                                     // 256 KB

    k1<<<512, 256, 0, stream>>>(h, W, a, WhT, s1, s2);
    k2<<<1024, 256, 0, stream>>>(adj, WhT, s1, s2, out);
}